// Round 4
// baseline (179.887 us; speedup 1.0000x reference)
//
#include <hip/hip_runtime.h>

typedef unsigned short u16;
typedef __attribute__((ext_vector_type(8))) short short8;   // 8 bf16 (4 VGPRs)
typedef __attribute__((ext_vector_type(4))) float floatx4;  // 4 fp32 acc

#define QPITCH 72    // elems (144 B): 16B-aligned rows

__device__ __forceinline__ u16 f2bf(float x) {
    unsigned u = __float_as_uint(x);
    u += 0x7fffu + ((u >> 16) & 1u);   // round-to-nearest-even
    return (u16)(u >> 16);
}

__global__ __launch_bounds__(256)
void cosine_relation_kernel(const float* __restrict__ q,
                            const float* __restrict__ s,
                            float* __restrict__ out)
{
    __shared__ u16 smem[2 * 128 * QPITCH];   // 36864 B bf16 tiles
    __shared__ float rq[128];
    __shared__ float rs[128];
    u16* qt = smem;
    u16* st = smem + 128 * QPITCH;

    const int t   = threadIdx.x;
    const int blk = blockIdx.x;           // == (b*25 + i)*25 + j
    const int b   = blk / 625;
    const int rem = blk % 625;
    const int i   = rem / 25;
    const int j   = rem % 25;

    const float* qbase = q + (size_t)(b * 25 + i) * 8192;  // 128x64 fp32
    const float* sbase = s + (size_t)(b * 25 + j) * 8192;

    // ---- Stage fp32 -> bf16 LDS + fused fp32 row sum-of-squares ----
    const int row  = t >> 1;
    const int half = t & 1;
    {
        const float* gp = qbase + row * 64 + half * 32;
        u16*         lp = qt + row * QPITCH + half * 32;
        float ss = 0.f;
#pragma unroll
        for (int c = 0; c < 4; ++c) {
            float4 f0 = *(const float4*)(gp + c * 8);
            float4 f1 = *(const float4*)(gp + c * 8 + 4);
            ss += f0.x*f0.x + f0.y*f0.y + f0.z*f0.z + f0.w*f0.w;
            ss += f1.x*f1.x + f1.y*f1.y + f1.z*f1.z + f1.w*f1.w;
            short8 h;
            h[0] = (short)f2bf(f0.x); h[1] = (short)f2bf(f0.y);
            h[2] = (short)f2bf(f0.z); h[3] = (short)f2bf(f0.w);
            h[4] = (short)f2bf(f1.x); h[5] = (short)f2bf(f1.y);
            h[6] = (short)f2bf(f1.z); h[7] = (short)f2bf(f1.w);
            *(short8*)(lp + c * 8) = h;
        }
        ss += __shfl_xor(ss, 1);
        if (half == 0) rq[row] = 1.0f / fmaxf(sqrtf(ss), 1e-12f);
    }
    {
        const float* gp = sbase + row * 64 + half * 32;
        u16*         lp = st + row * QPITCH + half * 32;
        float ss = 0.f;
#pragma unroll
        for (int c = 0; c < 4; ++c) {
            float4 f0 = *(const float4*)(gp + c * 8);
            float4 f1 = *(const float4*)(gp + c * 8 + 4);
            ss += f0.x*f0.x + f0.y*f0.y + f0.z*f0.z + f0.w*f0.w;
            ss += f1.x*f1.x + f1.y*f1.y + f1.z*f1.z + f1.w*f1.w;
            short8 h;
            h[0] = (short)f2bf(f0.x); h[1] = (short)f2bf(f0.y);
            h[2] = (short)f2bf(f0.z); h[3] = (short)f2bf(f0.w);
            h[4] = (short)f2bf(f1.x); h[5] = (short)f2bf(f1.y);
            h[6] = (short)f2bf(f1.z); h[7] = (short)f2bf(f1.w);
            *(short8*)(lp + c * 8) = h;
        }
        ss += __shfl_xor(ss, 1);
        if (half == 0) rs[row] = 1.0f / fmaxf(sqrtf(ss), 1e-12f);
    }
    __syncthreads();

    // ---- MFMA: each wave computes a 64x64 sub-tile ----
    const int wave = t >> 6;
    const int lane = t & 63;
    const int quad = lane >> 4;
    const int l15  = lane & 15;
    const int m0   = (wave >> 1) * 64;
    const int n0   = (wave & 1) * 64;

    floatx4 acc[4][4] = {};
#pragma unroll
    for (int ks = 0; ks < 2; ++ks) {
        short8 af[4], bfr[4];
#pragma unroll
        for (int mt = 0; mt < 4; ++mt)
            af[mt] = *(const short8*)(qt + (m0 + mt * 16 + l15) * QPITCH + ks * 32 + quad * 8);
#pragma unroll
        for (int nt = 0; nt < 4; ++nt)
            bfr[nt] = *(const short8*)(st + (n0 + nt * 16 + l15) * QPITCH + ks * 32 + quad * 8);
#pragma unroll
        for (int mt = 0; mt < 4; ++mt)
#pragma unroll
            for (int nt = 0; nt < 4; ++nt)
                acc[mt][nt] = __builtin_amdgcn_mfma_f32_16x16x32_bf16(
                    af[mt], bfr[nt], acc[mt][nt], 0, 0, 0);
    }

    // ---- Epilogue: scale by rq[m]*rs[n], direct fp32 stores ----
    // C/D layout (probe-verified R3): row = quad*4 + r, col = lane&15.
    // Per store instr: 4 quads write 4 x 16 consecutive fp32 = 4 x 64B segs.
    float rsv[4];
#pragma unroll
    for (int nt = 0; nt < 4; ++nt) rsv[nt] = rs[n0 + nt * 16 + l15];
    float rqv[4][4];
#pragma unroll
    for (int mt = 0; mt < 4; ++mt)
#pragma unroll
        for (int r = 0; r < 4; ++r) rqv[mt][r] = rq[m0 + mt * 16 + quad * 4 + r];

    float* obase = out + (size_t)blk * 16384 + n0 + l15;
#pragma unroll
    for (int mt = 0; mt < 4; ++mt) {
#pragma unroll
        for (int r = 0; r < 4; ++r) {
            const int m = m0 + mt * 16 + quad * 4 + r;
            float* op = obase + m * 128;
#pragma unroll
            for (int nt = 0; nt < 4; ++nt)
                op[nt * 16] = acc[mt][nt][r] * rqv[mt][r] * rsv[nt];
        }
    }
}

extern "C" void kernel_launch(void* const* d_in, const int* in_sizes, int n_in,
                              void* d_out, int out_size, void* d_ws, size_t ws_size,
                              hipStream_t stream) {
    const float* q = (const float*)d_in[0];
    const float* s = (const float*)d_in[1];
    float* out = (float*)d_out;
    cosine_relation_kernel<<<2500, 256, 0, stream>>>(q, s, out);
}

// Round 5
// 176.406 us; speedup vs baseline: 1.0197x; 1.0197x over previous
//
#include <hip/hip_runtime.h>

typedef unsigned short u16;
typedef unsigned int u32;
typedef __attribute__((ext_vector_type(8))) short short8;    // 8 bf16 (4 VGPRs)
typedef __attribute__((ext_vector_type(4))) float floatx4;   // 4 fp32 acc
typedef __attribute__((ext_vector_type(4))) u32 uint4v;

#define QPITCH 72    // elems (144 B): 16B-aligned rows, conflict-free phases

// Pack two fp32 -> two bf16 (RNE) in one dword: low16=bf(a), high16=bf(b).
__device__ __forceinline__ u32 pack2bf(float a, float b) {
    u32 ua = __float_as_uint(a), ub = __float_as_uint(b);
    ua += 0x7fffu + ((ua >> 16) & 1u);   // RNE
    ub += 0x7fffu + ((ub >> 16) & 1u);
    // bytes: [ub31:24 | ub23:16 | ua31:24 | ua23:16]
    return __builtin_amdgcn_perm(ub, ua, 0x07060302);
}

__global__ __launch_bounds__(256, 4)
void cosine_relation_kernel(const float* __restrict__ q,
                            const float* __restrict__ s,
                            float* __restrict__ out)
{
    __shared__ u16 smem[2 * 128 * QPITCH];   // 36864 B: two 128x64 bf16 tiles
    u16* qt = smem;
    u16* st = smem + 128 * QPITCH;

    const int t   = threadIdx.x;
    const int blk = blockIdx.x;           // == (b*25 + i)*25 + j
    const int b   = blk / 625;
    const int rem = blk % 625;
    const int i   = rem / 25;
    const int j   = rem % 25;

    const float* qbase = q + (size_t)(b * 25 + i) * 8192;  // 128x64 fp32
    const float* sbase = s + (size_t)(b * 25 + j) * 8192;

    // ---- Stage: load fp32, row-L2-normalize in fp32, pack bf16 -> LDS ----
    // thread t: row = t>>1, half = t&1 (32 floats). Pair (t, t^1) shares a row.
    const int row  = t >> 1;
    const int half = t & 1;
#pragma unroll
    for (int tile = 0; tile < 2; ++tile) {
        const float* gp = (tile == 0 ? qbase : sbase) + row * 64 + half * 32;
        u16*         lp = (tile == 0 ? qt : st) + row * QPITCH + half * 32;
        float4 f[8];
#pragma unroll
        for (int c = 0; c < 8; ++c) f[c] = ((const float4*)gp)[c];
        float ss = 0.f;
#pragma unroll
        for (int c = 0; c < 8; ++c)
            ss += f[c].x*f[c].x + f[c].y*f[c].y + f[c].z*f[c].z + f[c].w*f[c].w;
        ss += __shfl_xor(ss, 1);                      // full-row sumsq
        const float r = 1.0f / fmaxf(sqrtf(ss), 1e-12f);  // torch eps semantics
#pragma unroll
        for (int c = 0; c < 4; ++c) {
            uint4v pk;
            pk.x = pack2bf(f[2*c].x * r,   f[2*c].y * r);
            pk.y = pack2bf(f[2*c].z * r,   f[2*c].w * r);
            pk.z = pack2bf(f[2*c+1].x * r, f[2*c+1].y * r);
            pk.w = pack2bf(f[2*c+1].z * r, f[2*c+1].w * r);
            *(uint4v*)(lp + c * 8) = pk;
        }
    }
    __syncthreads();

    // ---- MFMA: each wave computes a 64x64 sub-tile ----
    const int wave = t >> 6;
    const int lane = t & 63;
    const int quad = lane >> 4;
    const int l15  = lane & 15;
    const int m0   = (wave >> 1) * 64;
    const int n0   = (wave & 1) * 64;

    floatx4 acc[4][4] = {};
#pragma unroll
    for (int ks = 0; ks < 2; ++ks) {
        short8 af[4], bfr[4];
#pragma unroll
        for (int mt = 0; mt < 4; ++mt)
            af[mt] = *(const short8*)(qt + (m0 + mt * 16 + l15) * QPITCH + ks * 32 + quad * 8);
#pragma unroll
        for (int nt = 0; nt < 4; ++nt)
            bfr[nt] = *(const short8*)(st + (n0 + nt * 16 + l15) * QPITCH + ks * 32 + quad * 8);
#pragma unroll
        for (int mt = 0; mt < 4; ++mt)
#pragma unroll
            for (int nt = 0; nt < 4; ++nt)
                acc[mt][nt] = __builtin_amdgcn_mfma_f32_16x16x32_bf16(
                    af[mt], bfr[nt], acc[mt][nt], 0, 0, 0);
    }

    // ---- Epilogue: inputs pre-normalized, so acc IS the cosine. Bare stores.
    // C/D layout (probe-verified R3): row = quad*4 + r, col = lane&15.
    float* obase = out + (size_t)blk * 16384 + n0 + l15;
#pragma unroll
    for (int mt = 0; mt < 4; ++mt) {
#pragma unroll
        for (int r = 0; r < 4; ++r) {
            float* op = obase + (size_t)(m0 + mt * 16 + quad * 4 + r) * 128;
#pragma unroll
            for (int nt = 0; nt < 4; ++nt)
                op[nt * 16] = acc[mt][nt][r];
        }
    }
}

extern "C" void kernel_launch(void* const* d_in, const int* in_sizes, int n_in,
                              void* d_out, int out_size, void* d_ws, size_t ws_size,
                              hipStream_t stream) {
    const float* q = (const float*)d_in[0];
    const float* s = (const float*)d_in[1];
    float* out = (float*)d_out;
    cosine_relation_kernel<<<2500, 256, 0, stream>>>(q, s, out);
}